// Round 5
// baseline (2478.399 us; speedup 1.0000x reference)
//
#include <hip/hip_runtime.h>

typedef unsigned short u16;
typedef unsigned int   u32;
typedef unsigned long long u64;
typedef short s16x8 __attribute__((ext_vector_type(8)));
typedef float f32x4 __attribute__((ext_vector_type(4)));

#define S_LEN 2048
#define BATCH 64
#define H_DIM 300
#define HP    304   // padded N (output) dim
#define KP    320   // padded K (contraction) dim

// ws layout (bytes)
#define OFF_WPAD 0u         // 304*320*2 = 194,560
#define OFF_BIAS 196608u    // 304*4
#define OFF_FLAG 198656u    // 4
#define OFF_H    200704u    // 64*304*4 = 77,824
#define OFF_POOL 278528u    // 2048*304*4 = 2,490,368
#define OFF_WHH  2768896u   // 300*300*4 = 360,000 (pad to 364,544)
#define OFF_XP   3133440u   // CH*64*304*4 (f32)

__device__ __forceinline__ float bf2f(u16 u){
  union { u32 i; float f; } v; v.i = ((u32)u) << 16; return v.f;
}
__device__ __forceinline__ u16 f2bf(float f){
  u32 i = __float_as_uint(f);
  u32 r = (i + 0x7fffu + ((i >> 16) & 1u)) >> 16;
  return (u16)r;
}

// ---------------------------------------------------------------------------
// detect: f32 vs bf16 input storage. bf16 emb ~N(0,0.02^2) has exponent
// field < 135 always; f32 words read as u16 have ~uniform low-mantissa bits.
// ---------------------------------------------------------------------------
__global__ __launch_bounds__(256) void detect(const u16* __restrict__ emb_raw,
                                              int* __restrict__ flag){
  __shared__ int big;
  if (threadIdx.x == 0) big = 0;
  __syncthreads();
  int loc = 0;
  for (int i = threadIdx.x; i < 1024; i += 256){
    const u32 e = ((u32)emb_raw[i] >> 7) & 0xFFu;
    if (e >= 135u) loc = 1;
  }
  if (loc) atomicOr(&big, 1);
  __syncthreads();
  if (threadIdx.x == 0) *flag = big;   // 1 = f32 inputs, 0 = bf16 inputs
}

// ---------------------------------------------------------------------------
// prep: zero pooled/hstate; padded bf16 W_ih [304][320]; fused fp32 bias;
// f32 W_hh [300][300] copy (so recur's weight load is branch-free).
// ---------------------------------------------------------------------------
__global__ __launch_bounds__(256) void prep(
    const void* __restrict__ Wih_raw, const void* __restrict__ Whh_raw,
    const void* __restrict__ bih_raw, const void* __restrict__ bhh_raw,
    const int* __restrict__ flag,
    u16* __restrict__ Wpad, float* __restrict__ Whh32,
    float* __restrict__ biasp, float* __restrict__ pooled,
    float* __restrict__ hstate)
{
  const bool isf32 = (*flag != 0);
  const int idx = blockIdx.x * 256 + threadIdx.x;
  if (idx < S_LEN * HP) pooled[idx] = 0.f;
  if (idx < BATCH * HP) hstate[idx] = 0.f;
  if (idx < H_DIM * H_DIM){
    Whh32[idx] = isf32 ? ((const float*)Whh_raw)[idx]
                       : bf2f(((const u16*)Whh_raw)[idx]);
  }
  if (idx < HP * KP){
    const int n = idx / KP, k = idx % KP;
    u16 v = 0;
    if (n < H_DIM && k < H_DIM){
      v = isf32 ? f2bf(((const float*)Wih_raw)[n * H_DIM + k])
                : ((const u16*)Wih_raw)[n * H_DIM + k];
    }
    Wpad[idx] = v;
  }
  if (idx < HP){
    float bv = 0.f;
    if (idx < H_DIM){
      bv = isf32 ? (((const float*)bih_raw)[idx] + ((const float*)bhh_raw)[idx])
                 : (bf2f(((const u16*)bih_raw)[idx]) + bf2f(((const u16*)bhh_raw)[idx]));
    }
    biasp[idx] = bv;
  }
}

// ---------------------------------------------------------------------------
// xp_gemm: xp[mrel][n] = emb[x[s0*64+mrel]] . W_ih[n,:] + b_ih[n] + b_hh[n]
// One block = 64 m-rows, 4 waves, MFMA 16x16x32 bf16. xp stored f32.
// ---------------------------------------------------------------------------
__global__ __launch_bounds__(256) void xp_gemm(
    const int* __restrict__ x, const void* __restrict__ emb_raw,
    const int* __restrict__ flag,
    const u16* __restrict__ Wpad, const float* __restrict__ biasp,
    float* __restrict__ xp, int s0)
{
  __shared__ u16 A[64 * KP];                 // 40 KB
  const bool isf32 = (*flag != 0);
  const int tid = threadIdx.x;
  const int m0g = s0 * BATCH + blockIdx.x * 64;   // global m of row 0
  const int m0r = blockIdx.x * 64;                // chunk-relative

  // zero the k-pad tail (k 300..319) of each row
  for (int t = tid; t < 640; t += 256){
    const int row = t / 10, wd = t % 10;
    *(u32*)&A[row * KP + H_DIM + wd * 2] = 0u;
  }
  // gather 64 embedding rows, 4 elements per thread-iteration
  for (int t = tid; t < 64 * 75; t += 256){
    const int row = t / 75, off = t % 75;
    const int tok = x[m0g + row];
    u64 pk;
    if (isf32){
      const float4 v = *(const float4*)((const float*)emb_raw + (size_t)tok * H_DIM + off * 4);
      pk = (u64)f2bf(v.x) | ((u64)f2bf(v.y) << 16)
         | ((u64)f2bf(v.z) << 32) | ((u64)f2bf(v.w) << 48);
    } else {
      pk = *(const u64*)((const u16*)emb_raw + (size_t)tok * H_DIM + off * 4);
    }
    *(u64*)&A[row * KP + off * 4] = pk;
  }
  __syncthreads();

  const int wave = tid >> 6, lane = tid & 63;
  const int lm = lane & 15, lq = lane >> 4;

  f32x4 acc[19];
#pragma unroll
  for (int nt = 0; nt < 19; ++nt) acc[nt] = (f32x4){0.f, 0.f, 0.f, 0.f};

#pragma unroll
  for (int ks = 0; ks < 10; ++ks){
    const int k = ks * 32 + lq * 8;
    const s16x8 af = *(const s16x8*)&A[(wave * 16 + lm) * KP + k];
#pragma unroll
    for (int nt = 0; nt < 19; ++nt){
      const s16x8 bf = *(const s16x8*)&Wpad[(nt * 16 + lm) * KP + k];
      acc[nt] = __builtin_amdgcn_mfma_f32_16x16x32_bf16(af, bf, acc[nt], 0, 0, 0);
    }
  }
  // C/D layout: col = lane&15 (from B), row = (lane>>4)*4 + reg (verified)
#pragma unroll
  for (int nt = 0; nt < 19; ++nt){
    const int n = nt * 16 + lm;
    const float bv = biasp[n];
#pragma unroll
    for (int rr = 0; rr < 4; ++rr){
      const int m = m0r + wave * 16 + lq * 4 + rr;
      xp[(size_t)m * HP + n] = acc[nt][rr] + bv;
    }
  }
}

// ---------------------------------------------------------------------------
// recur: one block per batch element b. 960 threads = 15 waves.
// Wave c owns k-chunk [c*20, c*20+20) (15*20 = 300, no pad). Lane rg owns
// rows rg*5..+4 (guard row<300). w[5][20] = 100 VGPRs, register-resident
// under __launch_bounds__(960,4) (128-VGPR cap, 4 waves/SIMD).
// h in LDS fp32, wave-uniform float4 broadcasts; part[300][17] (both access
// phases bank-conflict-free: strides 85,17 coprime to 32).
// ---------------------------------------------------------------------------
__global__ __launch_bounds__(960, 4) void recur(
    const float* __restrict__ xp, const float* __restrict__ Whh32,
    float* __restrict__ hstate, float* __restrict__ pooled,
    float* __restrict__ dout, int s0, int len)
{
  const int b   = blockIdx.x;
  const int tid = threadIdx.x;
  const int c   = tid >> 6;        // 0..14: k-chunk
  const int rg  = tid & 63;        // row group

  __shared__ float h_f[KP];        // 320 floats, pads stay 0
  __shared__ float part[H_DIM][17];

  const int row0 = rg * 5;
  float w[5][20];
#pragma unroll
  for (int r = 0; r < 5; ++r){
    const int row = row0 + r;
#pragma unroll
    for (int p = 0; p < 20; ++p){
      w[r][p] = (row < H_DIM) ? Whh32[row * H_DIM + c * 20 + p] : 0.f;
    }
  }
  if (tid < KP) h_f[tid] = (tid < HP) ? hstate[b * HP + tid] : 0.f;

  const float* xpb = xp + (size_t)b * HP;        // chunk row t -> t*64+b
  float xv = (tid < HP) ? xpb[tid] : 0.f;        // t = 0
  __syncthreads();

  for (int t = 0; t < len; ++t){
    const float xpv = xv;
    const int tn = (t + 1 < len) ? (t + 1) : t;
    const float xnext = (tid < HP) ? xpb[(size_t)tn * (BATCH * HP) + tid] : 0.f;

    float a0 = 0.f, a1 = 0.f, a2 = 0.f, a3 = 0.f, a4 = 0.f;
#pragma unroll
    for (int q = 0; q < 5; ++q){
      const float4 hv = *(const float4*)&h_f[c * 20 + q * 4];
      a0 = fmaf(w[0][4*q+0], hv.x, a0); a0 = fmaf(w[0][4*q+1], hv.y, a0);
      a0 = fmaf(w[0][4*q+2], hv.z, a0); a0 = fmaf(w[0][4*q+3], hv.w, a0);
      a1 = fmaf(w[1][4*q+0], hv.x, a1); a1 = fmaf(w[1][4*q+1], hv.y, a1);
      a1 = fmaf(w[1][4*q+2], hv.z, a1); a1 = fmaf(w[1][4*q+3], hv.w, a1);
      a2 = fmaf(w[2][4*q+0], hv.x, a2); a2 = fmaf(w[2][4*q+1], hv.y, a2);
      a2 = fmaf(w[2][4*q+2], hv.z, a2); a2 = fmaf(w[2][4*q+3], hv.w, a2);
      a3 = fmaf(w[3][4*q+0], hv.x, a3); a3 = fmaf(w[3][4*q+1], hv.y, a3);
      a3 = fmaf(w[3][4*q+2], hv.z, a3); a3 = fmaf(w[3][4*q+3], hv.w, a3);
      a4 = fmaf(w[4][4*q+0], hv.x, a4); a4 = fmaf(w[4][4*q+1], hv.y, a4);
      a4 = fmaf(w[4][4*q+2], hv.z, a4); a4 = fmaf(w[4][4*q+3], hv.w, a4);
    }
    if (row0 < H_DIM){
      part[row0 + 0][c] = a0;
      part[row0 + 1][c] = a1;
      part[row0 + 2][c] = a2;
      part[row0 + 3][c] = a3;
      part[row0 + 4][c] = a4;
    }
    __syncthreads();

    if (tid < H_DIM){
      float sum = 0.f;
#pragma unroll
      for (int cc = 0; cc < 15; ++cc) sum += part[tid][cc];
      float h = sum + xpv;
      h = fmaxf(h, 0.f);
      const int s = s0 + t;
      atomicMax((u32*)(pooled + (size_t)s * HP + tid), __float_as_uint(h));
      h_f[tid] = h;
      if (s == S_LEN - 1) dout[S_LEN * 2 + b * H_DIM + tid] = h;  // f32 hidden
    }
    xv = xnext;
    __syncthreads();
  }
  if (tid < HP) hstate[b * HP + tid] = h_f[tid];
}

// ---------------------------------------------------------------------------
// outproj: out[s][c] = sum_i pooled[s][i] * W_out[c][i] + b_out[c]  (f32 out)
// ---------------------------------------------------------------------------
__global__ __launch_bounds__(128) void outproj(
    const float* __restrict__ pooled, const void* __restrict__ Wout_raw,
    const void* __restrict__ bout_raw, const int* __restrict__ flag,
    float* __restrict__ dout)
{
  const bool isf32 = (*flag != 0);
  const int s = blockIdx.x * 128 + threadIdx.x;   // 0..2047
  float a0, a1;
  if (isf32){ a0 = ((const float*)bout_raw)[0]; a1 = ((const float*)bout_raw)[1]; }
  else      { a0 = bf2f(((const u16*)bout_raw)[0]); a1 = bf2f(((const u16*)bout_raw)[1]); }
  for (int i = 0; i < H_DIM; ++i){
    const float p = pooled[(size_t)s * HP + i];
    float w0, w1;
    if (isf32){ w0 = ((const float*)Wout_raw)[i]; w1 = ((const float*)Wout_raw)[H_DIM + i]; }
    else      { w0 = bf2f(((const u16*)Wout_raw)[i]); w1 = bf2f(((const u16*)Wout_raw)[H_DIM + i]); }
    a0 = fmaf(p, w0, a0);
    a1 = fmaf(p, w1, a1);
  }
  dout[s * 2 + 0] = a0;
  dout[s * 2 + 1] = a1;
}

// ---------------------------------------------------------------------------
extern "C" void kernel_launch(void* const* d_in, const int* in_sizes, int n_in,
                              void* d_out, int out_size, void* d_ws, size_t ws_size,
                              hipStream_t stream)
{
  const int* x  = (const int*)d_in[0];
  const void* emb  = d_in[1];
  const void* Wih  = d_in[2];
  const void* Whh  = d_in[3];
  const void* bih  = d_in[4];
  const void* bhh  = d_in[5];
  const void* Wout = d_in[6];
  const void* bout = d_in[7];
  float* out = (float*)d_out;

  char* ws = (char*)d_ws;
  u16*   Wpad   = (u16*)(ws + OFF_WPAD);
  float* biasp  = (float*)(ws + OFF_BIAS);
  int*   flag   = (int*)(ws + OFF_FLAG);
  float* hstate = (float*)(ws + OFF_H);
  float* pooled = (float*)(ws + OFF_POOL);
  float* Whh32  = (float*)(ws + OFF_WHH);
  float* xp     = (float*)(ws + OFF_XP);

  // choose chunk size (steps) so OFF_XP + CH*64*304*4 fits in ws_size
  const size_t per_step = (size_t)BATCH * HP * 4;   // 77,824 B
  int CH = 16;
  const int cands[8] = {2048, 1024, 512, 256, 128, 64, 32, 16};
  for (int i = 0; i < 8; ++i){
    if ((size_t)OFF_XP + (size_t)cands[i] * per_step <= ws_size){ CH = cands[i]; break; }
  }
  const int nchunks = S_LEN / CH;

  detect<<<1, 256, 0, stream>>>((const u16*)emb, flag);
  prep<<<2432, 256, 0, stream>>>(Wih, Whh, bih, bhh, flag, Wpad, Whh32,
                                 biasp, pooled, hstate);
  for (int k = 0; k < nchunks; ++k){
    const int s0 = k * CH;
    xp_gemm<<<CH, 256, 0, stream>>>(x, emb, flag, Wpad, biasp, xp, s0);
    recur<<<64, 960, 0, stream>>>(xp, Whh32, hstate, pooled, out, s0, CH);
  }
  outproj<<<16, 128, 0, stream>>>(pooled, Wout, bout, flag, out);
}

// Round 6
// 2400.499 us; speedup vs baseline: 1.0325x; 1.0325x over previous
//
#include <hip/hip_runtime.h>

typedef unsigned short u16;
typedef unsigned int   u32;
typedef unsigned long long u64;
typedef short s16x8 __attribute__((ext_vector_type(8)));
typedef float f32x4 __attribute__((ext_vector_type(4)));

#define S_LEN 2048
#define BATCH 64
#define H_DIM 300
#define HP    304   // padded N (output) dim
#define KP    320   // padded K (contraction) dim for xp_gemm

// ws layout (bytes)
#define OFF_WPAD 0u         // 304*320*2 = 194,560
#define OFF_BIAS 196608u    // 304*4
#define OFF_FLAG 198656u    // 4
#define OFF_H    200704u    // 64*304*4 = 77,824
#define OFF_POOL 278528u    // 2048*304*4 = 2,490,368
#define OFF_WHH  2768896u   // 320*304*4 = 389,120
#define OFF_XP   3158016u   // CH*64*304*4 (f32)

__device__ __forceinline__ float bf2f(u16 u){
  union { u32 i; float f; } v; v.i = ((u32)u) << 16; return v.f;
}
__device__ __forceinline__ u16 f2bf(float f){
  u32 i = __float_as_uint(f);
  u32 r = (i + 0x7fffu + ((i >> 16) & 1u)) >> 16;
  return (u16)r;
}
__device__ __forceinline__ f32x4 fma4(f32x4 a, f32x4 b, f32x4 c){
#if __has_builtin(__builtin_elementwise_fma)
  return __builtin_elementwise_fma(a, b, c);
#else
  f32x4 r; r.x=fmaf(a.x,b.x,c.x); r.y=fmaf(a.y,b.y,c.y);
  r.z=fmaf(a.z,b.z,c.z); r.w=fmaf(a.w,b.w,c.w); return r;
#endif
}

// ---------------------------------------------------------------------------
// detect: f32 vs bf16 input storage (bf16 emb exponents < 135 always).
// ---------------------------------------------------------------------------
__global__ __launch_bounds__(256) void detect(const u16* __restrict__ emb_raw,
                                              int* __restrict__ flag){
  __shared__ int big;
  if (threadIdx.x == 0) big = 0;
  __syncthreads();
  int loc = 0;
  for (int i = threadIdx.x; i < 1024; i += 256){
    const u32 e = ((u32)emb_raw[i] >> 7) & 0xFFu;
    if (e >= 135u) loc = 1;
  }
  if (loc) atomicOr(&big, 1);
  __syncthreads();
  if (threadIdx.x == 0) *flag = big;   // 1 = f32 inputs, 0 = bf16 inputs
}

// ---------------------------------------------------------------------------
// prep: zero pooled/hstate; padded bf16 W_ih [304][320]; fused fp32 bias;
// zero-padded f32 W_hh [320 rows][304 cols].
// ---------------------------------------------------------------------------
__global__ __launch_bounds__(256) void prep(
    const void* __restrict__ Wih_raw, const void* __restrict__ Whh_raw,
    const void* __restrict__ bih_raw, const void* __restrict__ bhh_raw,
    const int* __restrict__ flag,
    u16* __restrict__ Wpad, float* __restrict__ Whh32,
    float* __restrict__ biasp, float* __restrict__ pooled,
    float* __restrict__ hstate)
{
  const bool isf32 = (*flag != 0);
  const int idx = blockIdx.x * 256 + threadIdx.x;
  if (idx < S_LEN * HP) pooled[idx] = 0.f;
  if (idx < BATCH * HP) hstate[idx] = 0.f;
  if (idx < 320 * 304){
    const int r = idx / 304, k = idx % 304;
    float wv = 0.f;
    if (r < H_DIM && k < H_DIM){
      wv = isf32 ? ((const float*)Whh_raw)[r * H_DIM + k]
                 : bf2f(((const u16*)Whh_raw)[r * H_DIM + k]);
    }
    Whh32[idx] = wv;
  }
  if (idx < HP * KP){
    const int n = idx / KP, k = idx % KP;
    u16 v = 0;
    if (n < H_DIM && k < H_DIM){
      v = isf32 ? f2bf(((const float*)Wih_raw)[n * H_DIM + k])
                : ((const u16*)Wih_raw)[n * H_DIM + k];
    }
    Wpad[idx] = v;
  }
  if (idx < HP){
    float bv = 0.f;
    if (idx < H_DIM){
      bv = isf32 ? (((const float*)bih_raw)[idx] + ((const float*)bhh_raw)[idx])
                 : (bf2f(((const u16*)bih_raw)[idx]) + bf2f(((const u16*)bhh_raw)[idx]));
    }
    biasp[idx] = bv;
  }
}

// ---------------------------------------------------------------------------
// xp_gemm: xp[mrel][n] = emb[x[s0*64+mrel]] . W_ih[n,:] + b_ih[n] + b_hh[n]
// One block = 64 m-rows, 4 waves, MFMA 16x16x32 bf16. xp stored f32.
// ---------------------------------------------------------------------------
__global__ __launch_bounds__(256) void xp_gemm(
    const int* __restrict__ x, const void* __restrict__ emb_raw,
    const int* __restrict__ flag,
    const u16* __restrict__ Wpad, const float* __restrict__ biasp,
    float* __restrict__ xp, int s0)
{
  __shared__ u16 A[64 * KP];                 // 40 KB
  const bool isf32 = (*flag != 0);
  const int tid = threadIdx.x;
  const int m0g = s0 * BATCH + blockIdx.x * 64;   // global m of row 0
  const int m0r = blockIdx.x * 64;                // chunk-relative

  for (int t = tid; t < 640; t += 256){
    const int row = t / 10, wd = t % 10;
    *(u32*)&A[row * KP + H_DIM + wd * 2] = 0u;
  }
  for (int t = tid; t < 64 * 75; t += 256){
    const int row = t / 75, off = t % 75;
    const int tok = x[m0g + row];
    u64 pk;
    if (isf32){
      const float4 v = *(const float4*)((const float*)emb_raw + (size_t)tok * H_DIM + off * 4);
      pk = (u64)f2bf(v.x) | ((u64)f2bf(v.y) << 16)
         | ((u64)f2bf(v.z) << 32) | ((u64)f2bf(v.w) << 48);
    } else {
      pk = *(const u64*)((const u16*)emb_raw + (size_t)tok * H_DIM + off * 4);
    }
    *(u64*)&A[row * KP + off * 4] = pk;
  }
  __syncthreads();

  const int wave = tid >> 6, lane = tid & 63;
  const int lm = lane & 15, lq = lane >> 4;

  f32x4 acc[19];
#pragma unroll
  for (int nt = 0; nt < 19; ++nt) acc[nt] = (f32x4){0.f, 0.f, 0.f, 0.f};

#pragma unroll
  for (int ks = 0; ks < 10; ++ks){
    const int k = ks * 32 + lq * 8;
    const s16x8 af = *(const s16x8*)&A[(wave * 16 + lm) * KP + k];
#pragma unroll
    for (int nt = 0; nt < 19; ++nt){
      const s16x8 bf = *(const s16x8*)&Wpad[(nt * 16 + lm) * KP + k];
      acc[nt] = __builtin_amdgcn_mfma_f32_16x16x32_bf16(af, bf, acc[nt], 0, 0, 0);
    }
  }
#pragma unroll
  for (int nt = 0; nt < 19; ++nt){
    const int n = nt * 16 + lm;
    const float bv = biasp[n];
#pragma unroll
    for (int rr = 0; rr < 4; ++rr){
      const int m = m0r + wave * 16 + lq * 4 + rr;
      xp[(size_t)m * HP + n] = acc[nt][rr] + bv;
    }
  }
}

// ---------------------------------------------------------------------------
// recur: one block per batch b. 768 threads = 12 waves. Wave c owns k-chunk
// [25c, 25c+25); lane l owns rows {4l..4l+3, 256+l}. Weights held as 30
// named f32x4 + 5 floats (SSA — cannot be demoted to scratch). h chunk
// broadcast via 1 ds_read_b32 + v_readlane into SGPRs; FMAs are f32x4
// (pk_fma). Partials: [12][320] LDS, b128+b32 writes, 76-thread f32x4 reduce.
// ---------------------------------------------------------------------------
#define RL(J) __uint_as_float(__builtin_amdgcn_readlane(hu, (J)))

__global__ __launch_bounds__(768, 3) void recur(
    const float* __restrict__ xp, const float* __restrict__ Whh32,
    float* __restrict__ hstate, float* __restrict__ pooled,
    float* __restrict__ dout, int s0, int len)
{
  const int b   = blockIdx.x;
  const int tid = threadIdx.x;
  const int c   = tid >> 6;        // k-chunk 0..11
  const int l   = tid & 63;
  const int k0  = c * 25;
  const int r0  = l * 4;           // rows r0..r0+3
  const int r4  = 256 + l;         // 5th row (300..319 are zero pad rows)

  __shared__ float hf[320];
  __shared__ float part[12 * 320];

  f32x4 w00,w01,w02,w03,w04,w05;
  f32x4 w10,w11,w12,w13,w14,w15;
  f32x4 w20,w21,w22,w23,w24,w25;
  f32x4 w30,w31,w32,w33,w34,w35;
  f32x4 w40,w41,w42,w43,w44,w45;
  float e0,e1,e2,e3,e4;

#define LOADW(R, ROW) { const float* wp = Whh32 + (size_t)(ROW) * 304 + k0;   \
  w##R##0=(f32x4){wp[0],wp[1],wp[2],wp[3]};                                   \
  w##R##1=(f32x4){wp[4],wp[5],wp[6],wp[7]};                                   \
  w##R##2=(f32x4){wp[8],wp[9],wp[10],wp[11]};                                 \
  w##R##3=(f32x4){wp[12],wp[13],wp[14],wp[15]};                               \
  w##R##4=(f32x4){wp[16],wp[17],wp[18],wp[19]};                               \
  w##R##5=(f32x4){wp[20],wp[21],wp[22],wp[23]};                               \
  e##R = wp[24]; }
  LOADW(0, r0)
  LOADW(1, r0 + 1)
  LOADW(2, r0 + 2)
  LOADW(3, r0 + 3)
  LOADW(4, r4)
#undef LOADW

  const float* xpb = xp + (size_t)b * HP;        // chunk row t -> t*64+b
  f32x4 xv = (f32x4){0.f,0.f,0.f,0.f};
  if (tid < 76){
    *(f32x4*)&hf[4 * tid] = *(const f32x4*)&hstate[b * HP + 4 * tid];
    xv = *(const f32x4*)&xpb[4 * tid];
  }
  __syncthreads();

  for (int t = 0; t < len; ++t){
    f32x4 xnext = (f32x4){0.f,0.f,0.f,0.f};
    if (tid < 76){
      const int tn = (t + 1 < len) ? (t + 1) : t;
      xnext = *(const f32x4*)&xpb[(size_t)tn * (BATCH * HP) + 4 * tid];
    }

    const float hl = hf[k0 + (l < 25 ? l : 0)];
    const u32 hu = __float_as_uint(hl);

    f32x4 a0 = (f32x4){0.f,0.f,0.f,0.f};
    f32x4 a1 = a0, a2 = a0, a3 = a0, a4 = a0;
#define DOTP(P) { const f32x4 hv = (f32x4){RL(4*(P)), RL(4*(P)+1), RL(4*(P)+2), RL(4*(P)+3)}; \
    a0 = fma4(w0##P, hv, a0); a1 = fma4(w1##P, hv, a1); a2 = fma4(w2##P, hv, a2);             \
    a3 = fma4(w3##P, hv, a3); a4 = fma4(w4##P, hv, a4); }
    DOTP(0) DOTP(1) DOTP(2) DOTP(3) DOTP(4) DOTP(5)
#undef DOTP
    const float h24 = RL(24);
    const f32x4 sv = (f32x4){
      fmaf(e0, h24, (a0.x + a0.y) + (a0.z + a0.w)),
      fmaf(e1, h24, (a1.x + a1.y) + (a1.z + a1.w)),
      fmaf(e2, h24, (a2.x + a2.y) + (a2.z + a2.w)),
      fmaf(e3, h24, (a3.x + a3.y) + (a3.z + a3.w))};
    const float s4 = fmaf(e4, h24, (a4.x + a4.y) + (a4.z + a4.w));

    *(f32x4*)&part[c * 320 + r0] = sv;
    part[c * 320 + r4] = s4;
    __syncthreads();

    if (tid < 76){
      f32x4 acc = xv;
#pragma unroll
      for (int cc = 0; cc < 12; ++cc) acc += *(const f32x4*)&part[cc * 320 + 4 * tid];
      acc.x = fmaxf(acc.x, 0.f); acc.y = fmaxf(acc.y, 0.f);
      acc.z = fmaxf(acc.z, 0.f); acc.w = fmaxf(acc.w, 0.f);
      const int s = s0 + t;
      if (tid < 75){
        u32* pb = (u32*)(pooled + (size_t)s * HP + 4 * tid);
        atomicMax(pb + 0, __float_as_uint(acc.x));
        atomicMax(pb + 1, __float_as_uint(acc.y));
        atomicMax(pb + 2, __float_as_uint(acc.z));
        atomicMax(pb + 3, __float_as_uint(acc.w));
        if (s == S_LEN - 1)
          *(f32x4*)&dout[S_LEN * 2 + b * H_DIM + 4 * tid] = acc;
      }
      *(f32x4*)&hf[4 * tid] = acc;
      xv = xnext;
    }
    __syncthreads();
  }
  if (tid < 76) *(f32x4*)&hstate[b * HP + 4 * tid] = *(const f32x4*)&hf[4 * tid];
}

// ---------------------------------------------------------------------------
// outproj: out[s][c] = sum_i pooled[s][i] * W_out[c][i] + b_out[c]  (f32 out)
// ---------------------------------------------------------------------------
__global__ __launch_bounds__(128) void outproj(
    const float* __restrict__ pooled, const void* __restrict__ Wout_raw,
    const void* __restrict__ bout_raw, const int* __restrict__ flag,
    float* __restrict__ dout)
{
  const bool isf32 = (*flag != 0);
  const int s = blockIdx.x * 128 + threadIdx.x;   // 0..2047
  float a0, a1;
  if (isf32){ a0 = ((const float*)bout_raw)[0]; a1 = ((const float*)bout_raw)[1]; }
  else      { a0 = bf2f(((const u16*)bout_raw)[0]); a1 = bf2f(((const u16*)bout_raw)[1]); }
  for (int i = 0; i < H_DIM; ++i){
    const float p = pooled[(size_t)s * HP + i];
    float w0, w1;
    if (isf32){ w0 = ((const float*)Wout_raw)[i]; w1 = ((const float*)Wout_raw)[H_DIM + i]; }
    else      { w0 = bf2f(((const u16*)Wout_raw)[i]); w1 = bf2f(((const u16*)Wout_raw)[H_DIM + i]); }
    a0 = fmaf(p, w0, a0);
    a1 = fmaf(p, w1, a1);
  }
  dout[s * 2 + 0] = a0;
  dout[s * 2 + 1] = a1;
}

// ---------------------------------------------------------------------------
extern "C" void kernel_launch(void* const* d_in, const int* in_sizes, int n_in,
                              void* d_out, int out_size, void* d_ws, size_t ws_size,
                              hipStream_t stream)
{
  const int* x  = (const int*)d_in[0];
  const void* emb  = d_in[1];
  const void* Wih  = d_in[2];
  const void* Whh  = d_in[3];
  const void* bih  = d_in[4];
  const void* bhh  = d_in[5];
  const void* Wout = d_in[6];
  const void* bout = d_in[7];
  float* out = (float*)d_out;

  char* ws = (char*)d_ws;
  u16*   Wpad   = (u16*)(ws + OFF_WPAD);
  float* biasp  = (float*)(ws + OFF_BIAS);
  int*   flag   = (int*)(ws + OFF_FLAG);
  float* hstate = (float*)(ws + OFF_H);
  float* pooled = (float*)(ws + OFF_POOL);
  float* Whh32  = (float*)(ws + OFF_WHH);
  float* xp     = (float*)(ws + OFF_XP);

  // choose chunk size (steps) so OFF_XP + CH*64*304*4 fits in ws_size
  const size_t per_step = (size_t)BATCH * HP * 4;   // 77,824 B
  int CH = 16;
  const int cands[8] = {2048, 1024, 512, 256, 128, 64, 32, 16};
  for (int i = 0; i < 8; ++i){
    if ((size_t)OFF_XP + (size_t)cands[i] * per_step <= ws_size){ CH = cands[i]; break; }
  }
  const int nchunks = S_LEN / CH;

  detect<<<1, 256, 0, stream>>>((const u16*)emb, flag);
  prep<<<2432, 256, 0, stream>>>(Wih, Whh, bih, bhh, flag, Wpad, Whh32,
                                 biasp, pooled, hstate);
  for (int k = 0; k < nchunks; ++k){
    const int s0 = k * CH;
    xp_gemm<<<CH, 256, 0, stream>>>(x, emb, flag, Wpad, biasp, xp, s0);
    recur<<<64, 768, 0, stream>>>(xp, Whh32, hstate, pooled, out, s0, CH);
  }
  outproj<<<16, 128, 0, stream>>>(pooled, Wout, bout, flag, out);
}